// Round 1
// baseline (520.923 us; speedup 1.0000x reference)
//
#include <hip/hip_runtime.h>
#include <math.h>

// Problem constants (from reference)
#define NQ   65536
#define MS   65536
#define H    32
#define IN   64
#define OUTC 64
#define K    15
#define QB   16      // queries per block in main kernel
#define KC   5       // k-chunk for LDS-staged 'weighted'

// ---------------------------------------------------------------------------
// Kernel A: fused KPConv -> pre-BN output [N, OUT] (fp32)
//   block = 256 threads (4 waves), QB=16 queries per block, grid = 4096
//   LDS: influence w[16][32][15] (30KB) + idx[16][32] (2KB) + wt[5][16][64] (20KB)
// ---------------------------------------------------------------------------
__global__ __launch_bounds__(256) void kpconv_main(
    const float* __restrict__ x, const float* __restrict__ qp,
    const float* __restrict__ sp, const int* __restrict__ inds,
    const float* __restrict__ kp, const float* __restrict__ W,
    float* __restrict__ out_raw)
{
    __shared__ float w_lds[QB][H][K];     // 30720 B
    __shared__ int   idx_lds[QB][H];      //  2048 B
    __shared__ float wt[KC][QB][IN];      // 20480 B

    const int tid = threadIdx.x;
    const int q0  = blockIdx.x * QB;

    // ---- Stage A: influence weights (512 (q,h) pairs, 2 per thread) ----
    for (int rep = 0; rep < 2; ++rep) {
        const int pair = tid + rep * 256;
        const int q = pair >> 5;          // 0..15
        const int h = pair & (H - 1);     // 0..31
        const int n = q0 + q;
        const int id = inds[n * H + h];
        idx_lds[q][h] = id;
        const float dx = sp[id * 3 + 0] - qp[n * 3 + 0];
        const float dy = sp[id * 3 + 1] - qp[n * 3 + 1];
        const float dz = sp[id * 3 + 2] - qp[n * 3 + 2];
#pragma unroll
        for (int k = 0; k < K; ++k) {
            const float ex = dx - kp[k * 3 + 0];
            const float ey = dy - kp[k * 3 + 1];
            const float ez = dz - kp[k * 3 + 2];
            const float sq = ex * ex + ey * ey + ez * ez;
            const float wv = 1.0f - sqrtf(sq) * (1.0f / 0.048f);
            w_lds[q][h][k] = wv > 0.0f ? wv : 0.0f;
        }
    }
    __syncthreads();

    // ---- Stage 1: weighted[q][k][lane] accumulation in registers ----
    // thread (wave wv_, lane): 4 queries (wv_*4+a), channel i = lane
    const int lane = tid & 63;
    const int wv_  = tid >> 6;
    float acc[4][K];
#pragma unroll
    for (int a = 0; a < 4; ++a)
#pragma unroll
        for (int k = 0; k < K; ++k) acc[a][k] = 0.0f;

#pragma unroll 4
    for (int h = 0; h < H; ++h) {
        float xv[4];
#pragma unroll
        for (int a = 0; a < 4; ++a) {
            const int id = idx_lds[wv_ * 4 + a][h];
            xv[a] = x[id * IN + lane];           // coalesced 256B per wave
        }
#pragma unroll
        for (int a = 0; a < 4; ++a)
#pragma unroll
            for (int k = 0; k < K; ++k)
                acc[a][k] += w_lds[wv_ * 4 + a][h][k] * xv[a];  // LDS broadcast
    }

    // ---- Stage 2: out[q][o] = sum_{k,i} weighted[q][k][i] * W[k][i][o] ----
    // k processed in 3 chunks of 5 via LDS round-trip of 'weighted'.
    float oacc[4] = {0.0f, 0.0f, 0.0f, 0.0f};
#pragma unroll
    for (int c = 0; c < 3; ++c) {
        __syncthreads();  // previous round done reading wt
#pragma unroll
        for (int a = 0; a < 4; ++a)
#pragma unroll
            for (int kk = 0; kk < KC; ++kk)
                wt[kk][wv_ * 4 + a][lane] = acc[a][c * KC + kk]; // conflict-free
        __syncthreads();

        for (int i4 = 0; i4 < 16; ++i4) {      // i4 outer: 5KB W slab hot in L1
#pragma unroll
            for (int kk = 0; kk < KC; ++kk) {
                float av[4][4];
#pragma unroll
                for (int a = 0; a < 4; ++a)
#pragma unroll
                    for (int j = 0; j < 4; ++j)
                        av[a][j] = wt[kk][wv_ * 4 + a][i4 * 4 + j]; // b128 bcast
                const float* Wrow = W + (c * KC + kk) * (IN * OUTC)
                                      + i4 * 4 * OUTC + lane;
#pragma unroll
                for (int j = 0; j < 4; ++j) {
                    const float wgt = Wrow[j * OUTC];  // coalesced, L1/L2-hot
#pragma unroll
                    for (int a = 0; a < 4; ++a)
                        oacc[a] += av[a][j] * wgt;
                }
            }
        }
    }

#pragma unroll
    for (int a = 0; a < 4; ++a)
        out_raw[(q0 + wv_ * 4 + a) * OUTC + lane] = oacc[a];
}

// ---------------------------------------------------------------------------
// Kernel B: per-block partial sums / sumsq per channel (256 blocks x 256 rows)
// ---------------------------------------------------------------------------
__global__ __launch_bounds__(256) void bn_partial(
    const float* __restrict__ out_raw, float* __restrict__ ws)
{
    __shared__ float ps[4][64];
    __shared__ float pq[4][64];
    const int c = threadIdx.x & 63;
    const int j = threadIdx.x >> 6;
    const int base = blockIdx.x * 256;
    float s = 0.0f, sq = 0.0f;
#pragma unroll 4
    for (int rr = 0; rr < 64; ++rr) {
        const int r = base + rr * 4 + j;
        const float v = out_raw[r * OUTC + c];
        s += v;
        sq += v * v;
    }
    ps[j][c] = s;
    pq[j][c] = sq;
    __syncthreads();
    if (j == 0) {
        s  = ps[0][c] + ps[1][c] + ps[2][c] + ps[3][c];
        sq = pq[0][c] + pq[1][c] + pq[2][c] + pq[3][c];
        ws[blockIdx.x * 64 + c]         = s;
        ws[16384 + blockIdx.x * 64 + c] = sq;
    }
}

// ---------------------------------------------------------------------------
// Kernel C: finalize BN scale/shift (1 block)
// ---------------------------------------------------------------------------
__global__ __launch_bounds__(256) void bn_finalize(
    const float* __restrict__ ws, const float* __restrict__ gamma,
    const float* __restrict__ beta, float* __restrict__ sc_sh)
{
    __shared__ float ps[4][64];
    __shared__ float pq[4][64];
    const int c = threadIdx.x & 63;
    const int j = threadIdx.x >> 6;
    float s = 0.0f, sq = 0.0f;
    for (int b = j; b < 256; b += 4) {
        s  += ws[b * 64 + c];
        sq += ws[16384 + b * 64 + c];
    }
    ps[j][c] = s;
    pq[j][c] = sq;
    __syncthreads();
    if (j == 0) {
        s  = ps[0][c] + ps[1][c] + ps[2][c] + ps[3][c];
        sq = pq[0][c] + pq[1][c] + pq[2][c] + pq[3][c];
        const float mean = s * (1.0f / (float)NQ);
        const float var  = sq * (1.0f / (float)NQ) - mean * mean;
        const float scale = gamma[c] / sqrtf(var + 1e-5f);
        sc_sh[c]      = scale;
        sc_sh[64 + c] = beta[c] - mean * scale;
    }
}

// ---------------------------------------------------------------------------
// Kernel D: apply BN + LeakyReLU(0.1) in place on d_out (float4)
// ---------------------------------------------------------------------------
__global__ __launch_bounds__(256) void bn_apply(
    float* __restrict__ out, const float* __restrict__ sc_sh)
{
    __shared__ float sc[64];
    __shared__ float sh[64];
    if (threadIdx.x < 64) {
        sc[threadIdx.x] = sc_sh[threadIdx.x];
        sh[threadIdx.x] = sc_sh[64 + threadIdx.x];
    }
    __syncthreads();
    const int idx = blockIdx.x * 256 + threadIdx.x;
#pragma unroll
    for (int it = 0; it < 4; ++it) {
        const int e = idx + it * 262144;          // float4 index, 1M total
        float4 v = ((const float4*)out)[e];
        const int cg = (e & 15) * 4;              // channel group
        float4 r;
        r.x = v.x * sc[cg + 0] + sh[cg + 0];
        r.y = v.y * sc[cg + 1] + sh[cg + 1];
        r.z = v.z * sc[cg + 2] + sh[cg + 2];
        r.w = v.w * sc[cg + 3] + sh[cg + 3];
        r.x = r.x >= 0.0f ? r.x : 0.1f * r.x;
        r.y = r.y >= 0.0f ? r.y : 0.1f * r.y;
        r.z = r.z >= 0.0f ? r.z : 0.1f * r.z;
        r.w = r.w >= 0.0f ? r.w : 0.1f * r.w;
        ((float4*)out)[e] = r;
    }
}

// ---------------------------------------------------------------------------
extern "C" void kernel_launch(void* const* d_in, const int* in_sizes, int n_in,
                              void* d_out, int out_size, void* d_ws, size_t ws_size,
                              hipStream_t stream)
{
    (void)in_sizes; (void)n_in; (void)out_size; (void)ws_size;
    const float* x     = (const float*)d_in[0];
    const float* qp    = (const float*)d_in[1];
    const float* sp    = (const float*)d_in[2];
    const int*   inds  = (const int*)d_in[3];
    const float* kp    = (const float*)d_in[4];
    const float* W     = (const float*)d_in[5];
    const float* gamma = (const float*)d_in[6];
    const float* beta  = (const float*)d_in[7];
    float* out = (float*)d_out;
    float* ws  = (float*)d_ws;   // [0,16384) psum | [16384,32768) psq | [32768,32896) scale/shift

    kpconv_main<<<NQ / QB, 256, 0, stream>>>(x, qp, sp, inds, kp, W, out);
    bn_partial<<<256, 256, 0, stream>>>(out, ws);
    bn_finalize<<<1, 256, 0, stream>>>(ws, gamma, beta, ws + 32768);
    bn_apply<<<1024, 256, 0, stream>>>(out, ws + 32768);
}

// Round 2
// 226.431 us; speedup vs baseline: 2.3006x; 2.3006x over previous
//
#include <hip/hip_runtime.h>
#include <math.h>

// Problem constants
#define NQ   65536
#define H    32
#define IN   64
#define OUTC 64
#define K    15
#define QB   16          // queries per block
#define S_XN 68          // xn row stride (bf16 elems): 64 + 4 pad (b64-align + bank spread)
#define S_WT 36          // wT row stride: 32 + 4 pad (b64-align)
#define AK   72          // Awt k_kp stride (64 + 8 swizzle: write-conflict fix)
#define AROW 1076        // Awt per-query row stride (>= 14*72+64; 1076/2=538 => 26 mod 32 bank stride)
#define INV_EXT (1.0f / 0.048f)

typedef __attribute__((ext_vector_type(8))) short short8;
typedef __attribute__((ext_vector_type(4))) short short4v;
typedef __attribute__((ext_vector_type(4))) float float4v;

static __device__ __forceinline__ short f2bf(float f) {
    union { float f; unsigned u; } v; v.f = f;
    unsigned r = (v.u + 0x7FFFu + ((v.u >> 16) & 1u)) >> 16;   // RNE
    return (short)r;
}

// ---------------------------------------------------------------------------
// Prep: repack W [15][64][64] fp32 -> stage-2 B-fragment dump order, bf16.
// Bfrag[((v*30 + t)*64 + lane)*8 + j] = W[kq][i][o],
//   kq = t>>1, i = (t&1)*32 + (lane>>4)*8 + j, o = v*16 + (lane&15)
// ---------------------------------------------------------------------------
__global__ __launch_bounds__(256) void prep_bfrag(
    const float* __restrict__ W, short* __restrict__ Bfrag)
{
    const int tid  = blockIdx.x * 256 + threadIdx.x;   // 0..61439
    const int j    = tid & 7;
    const int lane = (tid >> 3) & 63;
    const int rest = tid >> 9;                         // 0..119
    const int t    = rest % 30;
    const int v    = rest / 30;
    const int kq   = t >> 1;
    const int i    = (t & 1) * 32 + (lane >> 4) * 8 + j;
    const int o    = v * 16 + (lane & 15);
    Bfrag[tid] = f2bf(W[kq * 4096 + i * 64 + o]);
}

// ---------------------------------------------------------------------------
// Main: fused KPConv via dual MFMA. 4096 blocks x 256 threads (4 waves).
//   wave v owns n-tile v (16 channels) in both GEMMs.
// ---------------------------------------------------------------------------
__global__ __launch_bounds__(256, 3) void kpconv_mfma(
    const float* __restrict__ x, const float* __restrict__ qp,
    const float* __restrict__ sp, const int* __restrict__ inds,
    const float* __restrict__ kp, const short* __restrict__ Bfrag,
    float* __restrict__ out_raw)
{
    __shared__ __align__(16) short uni[QB * AROW];        // 34432 B: xn (stage1) / Awt (stage2)
    __shared__ __align__(16) short wT[QB * 16 * S_WT];    // 18432 B: w transposed [q][k][h]

    const int tid  = threadIdx.x;
    const int lane = tid & 63;
    const int wv   = tid >> 6;        // wave = n-tile
    const int quad = lane >> 4;
    const int ml   = lane & 15;
    const int q0   = blockIdx.x * QB;

    // ---- Stage A: influence weights -> wT[q][k][h] (bf16), k=15 row zeroed ----
    for (int rep = 0; rep < 2; ++rep) {
        const int pair = tid + rep * 256;
        const int q = pair >> 5, h = pair & 31;
        const int n = q0 + q;
        const int id = inds[n * H + h];
        const float dx = sp[id * 3 + 0] - qp[n * 3 + 0];
        const float dy = sp[id * 3 + 1] - qp[n * 3 + 1];
        const float dz = sp[id * 3 + 2] - qp[n * 3 + 2];
#pragma unroll
        for (int k = 0; k < K; ++k) {
            const float ex = dx - kp[k * 3 + 0];
            const float ey = dy - kp[k * 3 + 1];
            const float ez = dz - kp[k * 3 + 2];
            const float sq = ex * ex + ey * ey + ez * ez;
            float wval = 1.0f - sqrtf(sq) * INV_EXT;
            wval = wval > 0.0f ? wval : 0.0f;
            wT[(q * 16 + k) * S_WT + h] = f2bf(wval);
        }
        wT[(q * 16 + K) * S_WT + h] = 0;   // zero pad row (MFMA m=15)
    }
    __syncthreads();

    // ---- Stage 1: per query C[k][i] = sum_h w[h][k] * xn[h][i], MFMA 16x16x32 ----
    float4v frag[QB];
#pragma unroll
    for (int qg = 0; qg < QB; ++qg) frag[qg] = (float4v){0.f, 0.f, 0.f, 0.f};

    short* xn = uni;   // [4 q_loc][32 h][S_XN] bf16, natural layout

    for (int b = 0; b < 4; ++b) {
        // stage gather: wave v stages query q0+4b+v (32 rows, 8 rounds of 4)
        const int qg_s = 4 * b + wv;
        const int ibase = (q0 + qg_s) * H;
#pragma unroll
        for (int j = 0; j < 8; ++j) {
            const int h = j * 4 + quad;
            const int id = inds[ibase + h];                 // quad-uniform (broadcast)
            const float4 xv = *(const float4*)(x + id * IN + ml * 4);
            short4v p;
            p[0] = f2bf(xv.x); p[1] = f2bf(xv.y); p[2] = f2bf(xv.z); p[3] = f2bf(xv.w);
            *(short4v*)&xn[(wv * H + h) * S_XN + ml * 4] = p;   // ds_write_b64
        }
        __syncthreads();
        // MFMA: 4 queries of this sub-batch, n-tile = wv
#pragma unroll
        for (int ql = 0; ql < 4; ++ql) {
            const int qg = 4 * b + ql;
            const int arow = (qg * 16 + ml) * S_WT + quad * 8;
            const short4v alo = *(const short4v*)&wT[arow];
            const short4v ahi = *(const short4v*)&wT[arow + 4];
            short8 a;
#pragma unroll
            for (int e = 0; e < 4; ++e) { a[e] = alo[e]; a[e + 4] = ahi[e]; }
            short8 bb;
#pragma unroll
            for (int j = 0; j < 8; ++j)
                bb[j] = xn[(ql * H + quad * 8 + j) * S_XN + wv * 16 + ml];
            frag[qg] = __builtin_amdgcn_mfma_f32_16x16x32_bf16(a, bb, frag[qg], 0, 0, 0);
        }
        __syncthreads();   // before next sub-batch overwrites xn (and before Awt reuse)
    }

    // ---- Round trip: C-frags -> Awt[q][kq*72 + i] bf16 (stage-2 A layout) ----
#pragma unroll
    for (int qg = 0; qg < QB; ++qg) {
#pragma unroll
        for (int r = 0; r < 4; ++r) {
            const int kq = quad * 4 + r;        // C row = quad*4 + reg
            if (kq < K)
                uni[qg * AROW + kq * AK + wv * 16 + ml] = f2bf(frag[qg][r]);
        }
    }
    __syncthreads();

    // ---- Stage 2: out[q][o] = sum_{k'} Awt[q][k'] * W'[k'][o], 30 K-steps ----
    float4v acc = (float4v){0.f, 0.f, 0.f, 0.f};
    const short* bptr = Bfrag + (wv * 30) * 512 + lane * 8;
#pragma unroll 2
    for (int t = 0; t < 30; ++t) {
        const int abase = ml * AROW + (t >> 1) * AK + (t & 1) * 32 + quad * 8;
        const short4v alo = *(const short4v*)&uni[abase];
        const short4v ahi = *(const short4v*)&uni[abase + 4];
        short8 a;
#pragma unroll
        for (int e = 0; e < 4; ++e) { a[e] = alo[e]; a[e + 4] = ahi[e]; }
        const short8 bb = *(const short8*)(bptr + t * 512);   // coalesced 1KB/wave
        acc = __builtin_amdgcn_mfma_f32_16x16x32_bf16(a, bb, acc, 0, 0, 0);
    }

#pragma unroll
    for (int r = 0; r < 4; ++r)
        out_raw[(q0 + quad * 4 + r) * OUTC + wv * 16 + ml] = acc[r];
}

// ---------------------------------------------------------------------------
// BatchNorm chain (unchanged from round 1)
// ---------------------------------------------------------------------------
__global__ __launch_bounds__(256) void bn_partial(
    const float* __restrict__ out_raw, float* __restrict__ ws)
{
    __shared__ float ps[4][64];
    __shared__ float pq[4][64];
    const int c = threadIdx.x & 63;
    const int j = threadIdx.x >> 6;
    const int base = blockIdx.x * 256;
    float s = 0.0f, sq = 0.0f;
#pragma unroll 4
    for (int rr = 0; rr < 64; ++rr) {
        const int r = base + rr * 4 + j;
        const float v = out_raw[r * OUTC + c];
        s += v; sq += v * v;
    }
    ps[j][c] = s; pq[j][c] = sq;
    __syncthreads();
    if (j == 0) {
        s  = ps[0][c] + ps[1][c] + ps[2][c] + ps[3][c];
        sq = pq[0][c] + pq[1][c] + pq[2][c] + pq[3][c];
        ws[blockIdx.x * 64 + c]         = s;
        ws[16384 + blockIdx.x * 64 + c] = sq;
    }
}

__global__ __launch_bounds__(256) void bn_finalize(
    const float* __restrict__ ws, const float* __restrict__ gamma,
    const float* __restrict__ beta, float* __restrict__ sc_sh)
{
    __shared__ float ps[4][64];
    __shared__ float pq[4][64];
    const int c = threadIdx.x & 63;
    const int j = threadIdx.x >> 6;
    float s = 0.0f, sq = 0.0f;
    for (int b = j; b < 256; b += 4) {
        s  += ws[b * 64 + c];
        sq += ws[16384 + b * 64 + c];
    }
    ps[j][c] = s; pq[j][c] = sq;
    __syncthreads();
    if (j == 0) {
        s  = ps[0][c] + ps[1][c] + ps[2][c] + ps[3][c];
        sq = pq[0][c] + pq[1][c] + pq[2][c] + pq[3][c];
        const float mean = s * (1.0f / (float)NQ);
        const float var  = sq * (1.0f / (float)NQ) - mean * mean;
        const float scale = gamma[c] / sqrtf(var + 1e-5f);
        sc_sh[c]      = scale;
        sc_sh[64 + c] = beta[c] - mean * scale;
    }
}

__global__ __launch_bounds__(256) void bn_apply(
    float* __restrict__ out, const float* __restrict__ sc_sh)
{
    __shared__ float sc[64];
    __shared__ float sh[64];
    if (threadIdx.x < 64) {
        sc[threadIdx.x] = sc_sh[threadIdx.x];
        sh[threadIdx.x] = sc_sh[64 + threadIdx.x];
    }
    __syncthreads();
    const int idx = blockIdx.x * 256 + threadIdx.x;
#pragma unroll
    for (int it = 0; it < 4; ++it) {
        const int e = idx + it * 262144;
        float4 v = ((const float4*)out)[e];
        const int cg = (e & 15) * 4;
        float4 r;
        r.x = v.x * sc[cg + 0] + sh[cg + 0];
        r.y = v.y * sc[cg + 1] + sh[cg + 1];
        r.z = v.z * sc[cg + 2] + sh[cg + 2];
        r.w = v.w * sc[cg + 3] + sh[cg + 3];
        r.x = r.x >= 0.0f ? r.x : 0.1f * r.x;
        r.y = r.y >= 0.0f ? r.y : 0.1f * r.y;
        r.z = r.z >= 0.0f ? r.z : 0.1f * r.z;
        r.w = r.w >= 0.0f ? r.w : 0.1f * r.w;
        ((float4*)out)[e] = r;
    }
}

// ---------------------------------------------------------------------------
extern "C" void kernel_launch(void* const* d_in, const int* in_sizes, int n_in,
                              void* d_out, int out_size, void* d_ws, size_t ws_size,
                              hipStream_t stream)
{
    (void)in_sizes; (void)n_in; (void)out_size; (void)ws_size;
    const float* x     = (const float*)d_in[0];
    const float* qp    = (const float*)d_in[1];
    const float* sp    = (const float*)d_in[2];
    const int*   inds  = (const int*)d_in[3];
    const float* kp    = (const float*)d_in[4];
    const float* W     = (const float*)d_in[5];
    const float* gamma = (const float*)d_in[6];
    const float* beta  = (const float*)d_in[7];
    float* out = (float*)d_out;

    short* Bfrag = (short*)d_ws;                          // 61440 bf16 = 122880 B
    float* wsf   = (float*)((char*)d_ws + 131072);        // BN scratch

    prep_bfrag<<<240, 256, 0, stream>>>(W, Bfrag);
    kpconv_mfma<<<NQ / QB, 256, 0, stream>>>(x, qp, sp, inds, kp, Bfrag, out);
    bn_partial<<<256, 256, 0, stream>>>(out, wsf);
    bn_finalize<<<1, 256, 0, stream>>>(wsf, gamma, beta, wsf + 32768);
    bn_apply<<<1024, 256, 0, stream>>>(out, wsf + 32768);
}

// Round 4
// 161.962 us; speedup vs baseline: 3.2163x; 1.3980x over previous
//
#include <hip/hip_runtime.h>
#include <math.h>

// Problem constants
#define NQ   65536
#define H    32
#define IN   64
#define OUTC 64
#define K    15
#define QB   16          // queries per block
#define S_XN 68          // xn row stride (bf16 elems)
#define S_WT 36          // wT row stride
#define AK   72          // Awt k_kp stride (bank swizzle)
#define AROW 1076        // Awt per-query row stride (538 dwords -> 26 mod 32)
#define INV_EXT (1.0f / 0.048f)

// d_ws layout (bytes)
#define OFF_PSUM  131072                       // [2][64][4096] float = 2 MB
#define OFF_SCSH  (OFF_PSUM + 2097152)         // 128 floats
#define OFF_XBF   (OFF_SCSH + 1024)            // x in bf16: 8 MB
#define NEED_BF16 (OFF_XBF + (size_t)NQ * IN * 2)

typedef __attribute__((ext_vector_type(8))) short short8;
typedef __attribute__((ext_vector_type(4))) short short4v;
typedef __attribute__((ext_vector_type(4))) float float4v;

// round-to-nearest (ties up): 2 VALU ops
static __device__ __forceinline__ unsigned short f2bf(float f) {
    return (unsigned short)((__float_as_uint(f) + 0x8000u) >> 16);
}
static __device__ __forceinline__ unsigned pk2(float a, float b) {
    return (__float_as_uint(a) + 0x8000u) >> 16 |
           ((__float_as_uint(b) + 0x8000u) & 0xFFFF0000u);
}

// ---------------------------------------------------------------------------
// Prep: blocks [0,4096): x fp32 -> bf16 (coalesced, 4 elem/thread).
//       blocks [4096,4336): W repack -> stage-2 B-frag dump order (coalesced
//       READ of W, scattered write; inverse of the R2 mapping).
// ---------------------------------------------------------------------------
__global__ __launch_bounds__(256) void prep_all(
    const float* __restrict__ W, const float* __restrict__ x,
    short* __restrict__ Bfrag, unsigned short* __restrict__ xbf, int do_x)
{
    const int b = blockIdx.x;
    if (b < 4096) {
        if (do_x) {
            const int t = b * 256 + threadIdx.x;      // float4 index
            const float4 v = ((const float4*)x)[t];
            uint2 p; p.x = pk2(v.x, v.y); p.y = pk2(v.z, v.w);
            ((uint2*)xbf)[t] = p;
        }
    } else {
        const int t2 = (b - 4096) * 256 + threadIdx.x;   // flat W index, coalesced
        const int o  = t2 & 63;
        const int i  = (t2 >> 6) & 63;
        const int kq = t2 >> 12;                          // 0..14
        const int t  = kq * 2 + (i >> 5);
        const int lane = ((i >> 3) & 3) * 16 + (o & 15);
        const int v  = o >> 4;
        const int j  = i & 7;
        Bfrag[((v * 30 + t) * 64 + lane) * 8 + j] = (short)f2bf(W[t2]);
    }
}

// ---------------------------------------------------------------------------
// Main: fused KPConv via dual MFMA + BN partial sums in epilogue.
// LDS union: phase1 = xn(8704 shorts)+wT(9216 shorts); phase2 = Awt(17216).
// ---------------------------------------------------------------------------
template<bool BFX>
__global__ __launch_bounds__(256, 4) void kpconv_mfma(
    const float* __restrict__ x, const unsigned short* __restrict__ xbf,
    const float* __restrict__ qp, const float* __restrict__ sp,
    const int* __restrict__ inds, const float* __restrict__ kp,
    const short* __restrict__ Bfrag, float* __restrict__ out_raw,
    float* __restrict__ psum)
{
    __shared__ __align__(16) short lds[17920];            // 35840 B -> 4 blk/CU
    short* xn  = lds;                                     // [4][32][S_XN]
    short* wT  = lds + 8704;                              // [16][16][S_WT]
    short* Awt = lds;                                     // phase 2

    const int tid  = threadIdx.x;
    const int lane = tid & 63;
    const int wv   = tid >> 6;
    const int quad = lane >> 4;
    const int ml   = lane & 15;
    const int q0   = blockIdx.x * QB;

    // ---- Stage A: influence weights -> wT[q][k][h] bf16, k=15 row zeroed ----
    for (int rep = 0; rep < 2; ++rep) {
        const int pair = tid + rep * 256;
        const int q = pair >> 5, h = pair & 31;
        const int n = q0 + q;
        const int id = inds[n * H + h];
        const float dx = sp[id * 3 + 0] - qp[n * 3 + 0];
        const float dy = sp[id * 3 + 1] - qp[n * 3 + 1];
        const float dz = sp[id * 3 + 2] - qp[n * 3 + 2];
#pragma unroll
        for (int k = 0; k < K; ++k) {
            const float ex = dx - kp[k * 3 + 0];
            const float ey = dy - kp[k * 3 + 1];
            const float ez = dz - kp[k * 3 + 2];
            const float sq = ex * ex + ey * ey + ez * ez;
            float wval = 1.0f - __builtin_amdgcn_sqrtf(sq) * INV_EXT;
            wval = wval > 0.0f ? wval : 0.0f;
            wT[(q * 16 + k) * S_WT + h] = (short)f2bf(wval);
        }
        wT[(q * 16 + K) * S_WT + h] = 0;
    }
    __syncthreads();

    // ---- Stage 1: per query C[k][i] = sum_h w[h][k]*xn[h][i] (MFMA) ----
    float4v frag[QB];
#pragma unroll
    for (int qg = 0; qg < QB; ++qg) frag[qg] = (float4v){0.f, 0.f, 0.f, 0.f};

    for (int b = 0; b < 4; ++b) {
        const int qg_s = 4 * b + wv;                 // wave stages one query
        const int ibase = (q0 + qg_s) * H;
#pragma unroll
        for (int j = 0; j < 8; ++j) {
            const int h = j * 4 + quad;
            const int id = inds[ibase + h];          // quad-uniform broadcast
            if (BFX) {
                const short4v xv = *(const short4v*)((const short*)xbf + id * IN + ml * 4);
                *(short4v*)&xn[(wv * H + h) * S_XN + ml * 4] = xv;
            } else {
                const float4 xv = *(const float4*)(x + id * IN + ml * 4);
                short4v p;
                p[0] = (short)f2bf(xv.x); p[1] = (short)f2bf(xv.y);
                p[2] = (short)f2bf(xv.z); p[3] = (short)f2bf(xv.w);
                *(short4v*)&xn[(wv * H + h) * S_XN + ml * 4] = p;
            }
        }
        __syncthreads();
#pragma unroll
        for (int ql = 0; ql < 4; ++ql) {
            const int qg = 4 * b + ql;
            const int arow = (qg * 16 + ml) * S_WT + quad * 8;
            const short4v alo = *(const short4v*)&wT[arow];
            const short4v ahi = *(const short4v*)&wT[arow + 4];
            short8 a;
#pragma unroll
            for (int e = 0; e < 4; ++e) { a[e] = alo[e]; a[e + 4] = ahi[e]; }
            short8 bb;
#pragma unroll
            for (int j = 0; j < 8; ++j)
                bb[j] = xn[(ql * H + quad * 8 + j) * S_XN + wv * 16 + ml];
            frag[qg] = __builtin_amdgcn_mfma_f32_16x16x32_bf16(a, bb, frag[qg], 0, 0, 0);
        }
        __syncthreads();
    }

    // ---- Round trip: C-frags -> Awt (stage-2 A layout, bf16) ----
#pragma unroll
    for (int qg = 0; qg < QB; ++qg) {
#pragma unroll
        for (int r = 0; r < 4; ++r) {
            const int kq = quad * 4 + r;
            if (kq < K)
                Awt[qg * AROW + kq * AK + wv * 16 + ml] = (short)f2bf(frag[qg][r]);
        }
    }
    __syncthreads();

    // ---- Stage 2: out[q][o] = sum_{k'} Awt[q][k'] * W'[k'][o] ----
    float4v acc = (float4v){0.f, 0.f, 0.f, 0.f};
    const short* bptr = Bfrag + (wv * 30) * 512 + lane * 8;
#pragma unroll 2
    for (int t = 0; t < 30; ++t) {
        const int abase = ml * AROW + (t >> 1) * AK + (t & 1) * 32 + quad * 8;
        const short4v alo = *(const short4v*)&Awt[abase];
        const short4v ahi = *(const short4v*)&Awt[abase + 4];
        short8 a;
#pragma unroll
        for (int e = 0; e < 4; ++e) { a[e] = alo[e]; a[e + 4] = ahi[e]; }
        const short8 bb = *(const short8*)(bptr + t * 512);
        acc = __builtin_amdgcn_mfma_f32_16x16x32_bf16(a, bb, acc, 0, 0, 0);
    }

    // ---- Epilogue: write raw out + per-block channel sums (BN partials) ----
    float s = 0.f, s2 = 0.f;
#pragma unroll
    for (int r = 0; r < 4; ++r) {
        const float v = acc[r];
        out_raw[(q0 + quad * 4 + r) * OUTC + wv * 16 + ml] = v;
        s += v; s2 += v * v;
    }
    s  += __shfl_xor(s, 16, 64);  s  += __shfl_xor(s, 32, 64);
    s2 += __shfl_xor(s2, 16, 64); s2 += __shfl_xor(s2, 32, 64);
    if (quad == 0) {
        const int c = wv * 16 + ml;
        psum[c * 4096 + blockIdx.x]          = s;
        psum[262144 + c * 4096 + blockIdx.x] = s2;
    }
}

// ---------------------------------------------------------------------------
// BN stats: one block per channel, reduce 4096 partials -> scale/shift
// ---------------------------------------------------------------------------
__global__ __launch_bounds__(256) void bn_stats(
    const float* __restrict__ psum, const float* __restrict__ gamma,
    const float* __restrict__ beta, float* __restrict__ sc_sh)
{
    const int c = blockIdx.x;
    const int t = threadIdx.x;
    float s = 0.f, q = 0.f;
#pragma unroll
    for (int i = 0; i < 16; ++i) {
        s += psum[c * 4096 + t + i * 256];
        q += psum[262144 + c * 4096 + t + i * 256];
    }
    __shared__ float rs[4], rq[4];
#pragma unroll
    for (int off = 32; off; off >>= 1) {
        s += __shfl_down(s, off, 64);
        q += __shfl_down(q, off, 64);
    }
    if ((t & 63) == 0) { rs[t >> 6] = s; rq[t >> 6] = q; }
    __syncthreads();
    if (t == 0) {
        s = rs[0] + rs[1] + rs[2] + rs[3];
        q = rq[0] + rq[1] + rq[2] + rq[3];
        const float mean = s * (1.0f / (float)NQ);
        const float var  = q * (1.0f / (float)NQ) - mean * mean;
        const float scale = gamma[c] / sqrtf(var + 1e-5f);
        sc_sh[c]      = scale;
        sc_sh[64 + c] = beta[c] - mean * scale;
    }
}

// ---------------------------------------------------------------------------
// Apply BN + LeakyReLU(0.1) in place (float4)
// ---------------------------------------------------------------------------
__global__ __launch_bounds__(256) void bn_apply(
    float* __restrict__ out, const float* __restrict__ sc_sh)
{
    __shared__ float sc[64];
    __shared__ float sh[64];
    if (threadIdx.x < 64) {
        sc[threadIdx.x] = sc_sh[threadIdx.x];
        sh[threadIdx.x] = sc_sh[64 + threadIdx.x];
    }
    __syncthreads();
    const int idx = blockIdx.x * 256 + threadIdx.x;
#pragma unroll
    for (int it = 0; it < 4; ++it) {
        const int e = idx + it * 262144;
        float4 v = ((const float4*)out)[e];
        const int cg = (e & 15) * 4;
        float4 r;
        r.x = v.x * sc[cg + 0] + sh[cg + 0];
        r.y = v.y * sc[cg + 1] + sh[cg + 1];
        r.z = v.z * sc[cg + 2] + sh[cg + 2];
        r.w = v.w * sc[cg + 3] + sh[cg + 3];
        r.x = r.x >= 0.0f ? r.x : 0.1f * r.x;
        r.y = r.y >= 0.0f ? r.y : 0.1f * r.y;
        r.z = r.z >= 0.0f ? r.z : 0.1f * r.z;
        r.w = r.w >= 0.0f ? r.w : 0.1f * r.w;
        ((float4*)out)[e] = r;
    }
}

// ---------------------------------------------------------------------------
extern "C" void kernel_launch(void* const* d_in, const int* in_sizes, int n_in,
                              void* d_out, int out_size, void* d_ws, size_t ws_size,
                              hipStream_t stream)
{
    (void)in_sizes; (void)n_in; (void)out_size;
    const float* x     = (const float*)d_in[0];
    const float* qp    = (const float*)d_in[1];
    const float* sp    = (const float*)d_in[2];
    const int*   inds  = (const int*)d_in[3];
    const float* kp    = (const float*)d_in[4];
    const float* W     = (const float*)d_in[5];
    const float* gamma = (const float*)d_in[6];
    const float* beta  = (const float*)d_in[7];
    float* out = (float*)d_out;

    short*          Bfrag = (short*)d_ws;
    float*          psum  = (float*)((char*)d_ws + OFF_PSUM);
    float*          sc_sh = (float*)((char*)d_ws + OFF_SCSH);
    unsigned short* xbf   = (unsigned short*)((char*)d_ws + OFF_XBF);

    const int use_bf = (ws_size >= NEED_BF16) ? 1 : 0;

    prep_all<<<4336, 256, 0, stream>>>(W, x, Bfrag, xbf, use_bf);
    if (use_bf)
        kpconv_mfma<true><<<NQ / QB, 256, 0, stream>>>(x, xbf, qp, sp, inds, kp, Bfrag, out, psum);
    else
        kpconv_mfma<false><<<NQ / QB, 256, 0, stream>>>(x, xbf, qp, sp, inds, kp, Bfrag, out, psum);
    bn_stats<<<64, 256, 0, stream>>>(psum, gamma, beta, sc_sh);
    bn_apply<<<1024, 256, 0, stream>>>(out, sc_sh);
}